// Round 1
// baseline (200.454 us; speedup 1.0000x reference)
//
#include <hip/hip_runtime.h>

// QNStepTD: n-step TD loss.
//   q_s_a[b]    = q[b, action[b]]
//   next_q[b]   = next_n_q[b, next_n_action[b]]
//   target[b]   = sum_{t<T} gamma^t * reward[t,b] + gamma^T * next_q[b] * (1 - done[b])
//   td[b]       = (q_s_a[b] - target[b])^2
//   loss        = mean(td * weight)
// d_out layout: [loss, td[0..B-1]]  (tuple return, concatenated flat)

__global__ __launch_bounds__(256) void qnstep_td_kernel(
    const float* __restrict__ q,
    const float* __restrict__ nq,
    const int*   __restrict__ act,
    const int*   __restrict__ nact,
    const float* __restrict__ rew,
    const int*   __restrict__ done,
    const float* __restrict__ w,
    const float* __restrict__ gamma_p,
    float*       __restrict__ out,
    int B, int N, int T, float invB)
{
    const int b = blockIdx.x * blockDim.x + threadIdx.x;
    const float gamma = gamma_p[0];

    float val = 0.0f;
    if (b < B) {
        // n-step discounted return over the reward rows (coalesced: stride-B rows)
        float f = 1.0f, tgt = 0.0f;
        #pragma unroll 8
        for (int t = 0; t < T; ++t) {
            tgt += f * rew[t * B + b];
            f *= gamma;
        }
        // bootstrap term, masked by done
        const float nd  = (done[b] != 0) ? 0.0f : 1.0f;
        const float nqv = nq[(long long)b * N + nact[b]];
        tgt += f * nqv * nd;

        const float qa = q[(long long)b * N + act[b]];
        const float d  = qa - tgt;
        const float td = d * d;
        out[1 + b] = td;
        val = td * w[b];
    }

    // wave-64 butterfly reduction
    #pragma unroll
    for (int off = 32; off > 0; off >>= 1)
        val += __shfl_down(val, off, 64);

    __shared__ float ssum[4];  // 256 threads / 64 lanes
    const int wave = threadIdx.x >> 6;
    const int lane = threadIdx.x & 63;
    if (lane == 0) ssum[wave] = val;
    __syncthreads();

    if (threadIdx.x == 0) {
        float s = ssum[0] + ssum[1] + ssum[2] + ssum[3];
        atomicAdd(out, s * invB);  // device-scope by default on gfx950
    }
}

extern "C" void kernel_launch(void* const* d_in, const int* in_sizes, int n_in,
                              void* d_out, int out_size, void* d_ws, size_t ws_size,
                              hipStream_t stream) {
    const float* q     = (const float*)d_in[0];
    const float* nq    = (const float*)d_in[1];
    const int*   act   = (const int*)d_in[2];
    const int*   nact  = (const int*)d_in[3];
    const float* rew   = (const float*)d_in[4];
    const int*   done  = (const int*)d_in[5];
    const float* w     = (const float*)d_in[6];
    const float* gamma = (const float*)d_in[7];

    const int B = in_sizes[2];            // action is (B,)
    const int N = in_sizes[0] / B;        // q is (B, N)
    const int T = in_sizes[4] / B;        // reward is (T, B)

    float* out = (float*)d_out;

    // d_out is poisoned 0xAA before every timed launch: zero the loss slot
    // ourselves (graph-capture-safe memset node).
    hipMemsetAsync(out, 0, sizeof(float), stream);

    const int block = 256;
    const int grid  = (B + block - 1) / block;
    qnstep_td_kernel<<<grid, block, 0, stream>>>(
        q, nq, act, nact, rew, done, w, gamma, out, B, N, T, 1.0f / (float)B);
}

// Round 2
// 188.253 us; speedup vs baseline: 1.0648x; 1.0648x over previous
//
#include <hip/hip_runtime.h>

// QNStepTD: n-step TD loss.
//   q_s_a[b]  = q[b, action[b]]
//   next_q[b] = next_n_q[b, next_n_action[b]]
//   target[b] = sum_{t<T} gamma^t * reward[t,b] + gamma^T * next_q[b] * (1-done[b])
//   td[b]     = (q_s_a[b] - target[b])^2
//   loss      = mean(td * weight)
// d_out layout: [loss, td[0..B-1]]
//
// R2: removed same-address atomicAdd (4096-way serialized RMW on out[0] was
// the suspected 74us bottleneck); two-stage reduction via d_ws. 4 samples per
// thread with int4/float4 stream loads for ILP + fewer instructions.

__global__ __launch_bounds__(256) void qnstep_td_main(
    const float* __restrict__ q,
    const float* __restrict__ nq,
    const int*   __restrict__ act,
    const int*   __restrict__ nact,
    const float* __restrict__ rew,
    const int*   __restrict__ done,
    const float* __restrict__ w,
    const float* __restrict__ gamma_p,
    float*       __restrict__ out,      // out[1..B] = td
    float*       __restrict__ partial,  // per-block sums (d_ws)
    int B, int N, int T)
{
    const int g  = blockIdx.x * blockDim.x + threadIdx.x;  // group of 4 samples
    const int b0 = g * 4;
    const float gamma = gamma_p[0];

    float val = 0.0f;
    if (b0 + 3 < B) {
        const int4   a4  = ((const int4*)act)[g];
        const int4   na4 = ((const int4*)nact)[g];
        const int4   d4  = ((const int4*)done)[g];
        const float4 w4  = ((const float4*)w)[g];

        // n-step discounted return (float4-coalesced reward rows)
        float t0 = 0.f, t1 = 0.f, t2 = 0.f, t3 = 0.f;
        float f = 1.0f;
        #pragma unroll 8
        for (int t = 0; t < T; ++t) {
            const float4 r4 = ((const float4*)(rew + (long long)t * B))[g];
            t0 += f * r4.x; t1 += f * r4.y; t2 += f * r4.z; t3 += f * r4.w;
            f *= gamma;
        }

        // gathers (one 4B element per 64B row; lanes hit consecutive lines)
        const float nq0 = nq[(long long)(b0 + 0) * N + na4.x];
        const float nq1 = nq[(long long)(b0 + 1) * N + na4.y];
        const float nq2 = nq[(long long)(b0 + 2) * N + na4.z];
        const float nq3 = nq[(long long)(b0 + 3) * N + na4.w];
        const float q0  = q [(long long)(b0 + 0) * N + a4.x];
        const float q1  = q [(long long)(b0 + 1) * N + a4.y];
        const float q2  = q [(long long)(b0 + 2) * N + a4.z];
        const float q3  = q [(long long)(b0 + 3) * N + a4.w];

        t0 += f * nq0 * (d4.x ? 0.f : 1.f);
        t1 += f * nq1 * (d4.y ? 0.f : 1.f);
        t2 += f * nq2 * (d4.z ? 0.f : 1.f);
        t3 += f * nq3 * (d4.w ? 0.f : 1.f);

        const float e0 = q0 - t0, e1 = q1 - t1, e2 = q2 - t2, e3 = q3 - t3;
        const float td0 = e0 * e0, td1 = e1 * e1, td2 = e2 * e2, td3 = e3 * e3;

        // out+1 is only 4B-aligned: scalar stores (writes are 4 MB, cheap)
        out[1 + b0 + 0] = td0;
        out[1 + b0 + 1] = td1;
        out[1 + b0 + 2] = td2;
        out[1 + b0 + 3] = td3;

        val = td0 * w4.x + td1 * w4.y + td2 * w4.z + td3 * w4.w;
    }

    // wave-64 reduction
    #pragma unroll
    for (int off = 32; off > 0; off >>= 1)
        val += __shfl_down(val, off, 64);

    __shared__ float ssum[4];
    const int wave = threadIdx.x >> 6;
    const int lane = threadIdx.x & 63;
    if (lane == 0) ssum[wave] = val;
    __syncthreads();

    if (threadIdx.x == 0)
        partial[blockIdx.x] = ssum[0] + ssum[1] + ssum[2] + ssum[3];
}

__global__ __launch_bounds__(1024) void qnstep_td_reduce(
    const float* __restrict__ partial, float* __restrict__ out,
    int n, float invB)
{
    const int tid = threadIdx.x;
    float v = (tid < n) ? partial[tid] : 0.0f;

    #pragma unroll
    for (int off = 32; off > 0; off >>= 1)
        v += __shfl_down(v, off, 64);

    __shared__ float ssum[16];
    if ((tid & 63) == 0) ssum[tid >> 6] = v;
    __syncthreads();

    if (tid == 0) {
        float s = 0.0f;
        #pragma unroll
        for (int i = 0; i < 16; ++i) s += ssum[i];
        out[0] = s * invB;  // overwrites poison; no memset needed
    }
}

extern "C" void kernel_launch(void* const* d_in, const int* in_sizes, int n_in,
                              void* d_out, int out_size, void* d_ws, size_t ws_size,
                              hipStream_t stream) {
    const float* q     = (const float*)d_in[0];
    const float* nq    = (const float*)d_in[1];
    const int*   act   = (const int*)d_in[2];
    const int*   nact  = (const int*)d_in[3];
    const float* rew   = (const float*)d_in[4];
    const int*   done  = (const int*)d_in[5];
    const float* w     = (const float*)d_in[6];
    const float* gamma = (const float*)d_in[7];

    const int B = in_sizes[2];            // action is (B,)
    const int N = in_sizes[0] / B;        // q is (B, N)
    const int T = in_sizes[4] / B;        // reward is (T, B)

    float* out     = (float*)d_out;
    float* partial = (float*)d_ws;        // gridA floats

    const int block = 256;
    const int gridA = (B + block * 4 - 1) / (block * 4);   // 1024 for B=1M

    qnstep_td_main<<<gridA, block, 0, stream>>>(
        q, nq, act, nact, rew, done, w, gamma, out, partial, B, N, T);
    qnstep_td_reduce<<<1, 1024, 0, stream>>>(
        partial, out, gridA, 1.0f / (float)B);
}

// Round 3
// 185.155 us; speedup vs baseline: 1.0826x; 1.0167x over previous
//
#include <hip/hip_runtime.h>

// QNStepTD: n-step TD loss.
//   target[b] = sum_{t<T} gamma^t*reward[t,b] + gamma^T*next_n_q[b,na[b]]*(1-done[b])
//   td[b]     = (q[b,a[b]] - target[b])^2 ; loss = mean(td*weight)
// d_out layout: [loss, td[0..B-1]]
//
// R3: gathers were the bottleneck (divergent wave64 loads: 64 distinct lines
// per instruction -> ~1000cyc/instr TA serialization; R1/R2 both floored at
// ~60-74us with HBM at 1.4TB/s and VALU ~1%). q/nq are read DENSELY (every
// 64B row gathered once), so stage 512-row tiles through LDS with perfectly
// coalesced float4 loads, gather via one ds_read_b32 per sample.

#define TILE_ROWS 512                 // samples per block (2 per thread)
#define BLOCK     256

__global__ __launch_bounds__(BLOCK) void qnstep_td_main(
    const float* __restrict__ q,
    const float* __restrict__ nq,
    const int*   __restrict__ act,
    const int*   __restrict__ nact,
    const float* __restrict__ rew,
    const int*   __restrict__ done,
    const float* __restrict__ w,
    const float* __restrict__ gamma_p,
    float*       __restrict__ out,      // out[1..B] = td
    float*       __restrict__ partial,  // per-block sums (d_ws)
    int B, int T)
{
    // fast path assumes N==16 (row == 64B == 4 float4) and B % TILE_ROWS == 0
    __shared__ float tile[TILE_ROWS * 16];          // 32 KB

    const int tid  = threadIdx.x;
    const long long base = (long long)blockIdx.x * TILE_ROWS;  // first sample
    const float gamma = gamma_p[0];

    // ---- per-sample scalars, coalesced 8B loads (2 samples/thread) ----
    const long long g = base / 2 + tid;             // index into *2-vectors
    const int2   a2  = ((const int2*)act)[g];
    const int2   na2 = ((const int2*)nact)[g];
    const int2   d2  = ((const int2*)done)[g];
    const float2 w2  = ((const float2*)w)[g];

    // ---- n-step return ----
    float t0 = 0.f, t1 = 0.f, f = 1.0f;
    #pragma unroll 8
    for (int t = 0; t < T; ++t) {
        const float2 r2 = ((const float2*)(rew + (long long)t * B))[g];
        t0 += f * r2.x; t1 += f * r2.y;
        f *= gamma;
    }

    const int s0 = tid * 2, s1 = tid * 2 + 1;       // local sample ids

    // ---- stage q tile: 512 rows * 64B = 2048 float4, coalesced ----
    float4* t4 = (float4*)tile;
    {
        const float4* q4 = (const float4*)q + base * 4;
        #pragma unroll
        for (int j = 0; j < 8; ++j)
            t4[tid + j * BLOCK] = q4[tid + j * BLOCK];
    }
    __syncthreads();
    const float qa0 = tile[s0 * 16 + a2.x];
    const float qa1 = tile[s1 * 16 + a2.y];
    __syncthreads();

    // ---- stage nq tile (reuse buffer) ----
    {
        const float4* nq4 = (const float4*)nq + base * 4;
        #pragma unroll
        for (int j = 0; j < 8; ++j)
            t4[tid + j * BLOCK] = nq4[tid + j * BLOCK];
    }
    __syncthreads();
    const float nqa0 = tile[s0 * 16 + na2.x];
    const float nqa1 = tile[s1 * 16 + na2.y];

    // ---- targets, td, store ----
    t0 += f * nqa0 * (d2.x ? 0.f : 1.f);
    t1 += f * nqa1 * (d2.y ? 0.f : 1.f);
    const float e0 = qa0 - t0, e1 = qa1 - t1;
    const float td0 = e0 * e0, td1 = e1 * e1;

    out[1 + base + s0] = td0;
    out[1 + base + s1] = td1;

    float val = td0 * w2.x + td1 * w2.y;

    // ---- block reduction -> partial[blk] ----
    #pragma unroll
    for (int off = 32; off > 0; off >>= 1)
        val += __shfl_down(val, off, 64);

    __shared__ float ssum[BLOCK / 64];
    const int wave = tid >> 6, lane = tid & 63;
    if (lane == 0) ssum[wave] = val;
    __syncthreads();
    if (tid == 0) {
        float s = 0.f;
        #pragma unroll
        for (int i = 0; i < BLOCK / 64; ++i) s += ssum[i];
        partial[blockIdx.x] = s;
    }
}

// generic fallback (any N, any B) — the R2 kernel, 1 sample/thread
__global__ __launch_bounds__(256) void qnstep_td_generic(
    const float* __restrict__ q, const float* __restrict__ nq,
    const int* __restrict__ act, const int* __restrict__ nact,
    const float* __restrict__ rew, const int* __restrict__ done,
    const float* __restrict__ w, const float* __restrict__ gamma_p,
    float* __restrict__ out, float* __restrict__ partial,
    int B, int N, int T)
{
    const int b = blockIdx.x * blockDim.x + threadIdx.x;
    const float gamma = gamma_p[0];
    float val = 0.0f;
    if (b < B) {
        float f = 1.0f, tgt = 0.0f;
        for (int t = 0; t < T; ++t) { tgt += f * rew[(long long)t * B + b]; f *= gamma; }
        const float nd = (done[b] != 0) ? 0.f : 1.f;
        tgt += f * nq[(long long)b * N + nact[b]] * nd;
        const float d = q[(long long)b * N + act[b]] - tgt;
        const float td = d * d;
        out[1 + b] = td;
        val = td * w[b];
    }
    #pragma unroll
    for (int off = 32; off > 0; off >>= 1) val += __shfl_down(val, off, 64);
    __shared__ float ssum[4];
    if ((threadIdx.x & 63) == 0) ssum[threadIdx.x >> 6] = val;
    __syncthreads();
    if (threadIdx.x == 0)
        partial[blockIdx.x] = ssum[0] + ssum[1] + ssum[2] + ssum[3];
}

__global__ __launch_bounds__(1024) void qnstep_td_reduce(
    const float* __restrict__ partial, float* __restrict__ out,
    int n, float invB)
{
    const int tid = threadIdx.x;
    float v = 0.0f;
    for (int i = tid; i < n; i += 1024) v += partial[i];

    #pragma unroll
    for (int off = 32; off > 0; off >>= 1)
        v += __shfl_down(v, off, 64);

    __shared__ float ssum[16];
    if ((tid & 63) == 0) ssum[tid >> 6] = v;
    __syncthreads();

    if (tid == 0) {
        float s = 0.0f;
        #pragma unroll
        for (int i = 0; i < 16; ++i) s += ssum[i];
        out[0] = s * invB;  // overwrites poison
    }
}

extern "C" void kernel_launch(void* const* d_in, const int* in_sizes, int n_in,
                              void* d_out, int out_size, void* d_ws, size_t ws_size,
                              hipStream_t stream) {
    const float* q     = (const float*)d_in[0];
    const float* nq    = (const float*)d_in[1];
    const int*   act   = (const int*)d_in[2];
    const int*   nact  = (const int*)d_in[3];
    const float* rew   = (const float*)d_in[4];
    const int*   done  = (const int*)d_in[5];
    const float* w     = (const float*)d_in[6];
    const float* gamma = (const float*)d_in[7];

    const int B = in_sizes[2];            // action is (B,)
    const int N = in_sizes[0] / B;        // q is (B, N)
    const int T = in_sizes[4] / B;        // reward is (T, B)

    float* out     = (float*)d_out;
    float* partial = (float*)d_ws;

    if (N == 16 && (B % TILE_ROWS) == 0) {
        const int grid = B / TILE_ROWS;   // 2048 for B=1M
        qnstep_td_main<<<grid, BLOCK, 0, stream>>>(
            q, nq, act, nact, rew, done, w, gamma, out, partial, B, T);
        qnstep_td_reduce<<<1, 1024, 0, stream>>>(partial, out, grid, 1.0f / (float)B);
    } else {
        const int grid = (B + 255) / 256;
        qnstep_td_generic<<<grid, 256, 0, stream>>>(
            q, nq, act, nact, rew, done, w, gamma, out, partial, B, N, T);
        qnstep_td_reduce<<<1, 1024, 0, stream>>>(partial, out, grid, 1.0f / (float)B);
    }
}